// Round 18
// baseline (250.032 us; speedup 1.0000x reference)
//
#include <hip/hip_runtime.h>
#include <hip/hip_bf16.h>

#define BB 64
#define SS 1024
#define DDIM 256

typedef unsigned short u16;
typedef unsigned int u32;
typedef __attribute__((ext_vector_type(4))) float f4;
typedef __attribute__((ext_vector_type(8))) short bf16x8;
typedef __attribute__((ext_vector_type(4))) short bf16x4;
typedef __attribute__((ext_vector_type(4))) float f32x4;

__device__ inline u16 f2b(float f) {
  unsigned int u = __float_as_uint(f);
  unsigned int r = (u + 0x7fffu + ((u >> 16) & 1u)) >> 16;
  return (u16)r;
}
__device__ inline float b2f(u16 v) {
  return __uint_as_float(((u32)v) << 16);
}

// ---------------------------------------------------------------------------
__global__ __launch_bounds__(256) void cast_x(const float* __restrict__ x,
                                              u16* __restrict__ xb, int n8) {
  int i = blockIdx.x * 256 + threadIdx.x;
  const int stride = gridDim.x * 256;
  for (; i < n8; i += stride) {
    f4 a = ((const f4*)x)[2 * i];
    f4 b = ((const f4*)x)[2 * i + 1];
    bf16x8 o;
    o[0] = f2b(a[0]); o[1] = f2b(a[1]); o[2] = f2b(a[2]); o[3] = f2b(a[3]);
    o[4] = f2b(b[0]); o[5] = f2b(b[1]); o[6] = f2b(b[2]); o[7] = f2b(b[3]);
    ((bf16x8*)xb)[i] = o;
  }
}

__global__ __launch_bounds__(256) void cast_w(const float* __restrict__ Wqkv,
                                              const float* __restrict__ Wout,
                                              u16* __restrict__ Wqkvt,
                                              u16* __restrict__ Woutt) {
  int t = blockIdx.x * 256 + threadIdx.x;
  if (t < 256 * 768) {
    int k = t / 768, n = t % 768;
    Wqkvt[n * 256 + k] = f2b(Wqkv[t]);
  }
  if (t < 256 * 256) {
    int k = t / 256, n = t % 256;
    Woutt[n * 256 + k] = f2b(Wout[t]);
  }
}

// ---------------------------------------------------------------------------
// MFMA GEMM v2 (round-15, kept): 128x256 tile, 8 waves, BK=64, reg-staged.
// ---------------------------------------------------------------------------
template <int EPI, int NXT>
__global__ __launch_bounds__(512) void gemm_mfma(
    const u16* __restrict__ A, const u16* __restrict__ Bt,
    const float* __restrict__ bias, float* __restrict__ outF,
    u16* __restrict__ Qb, u16* __restrict__ Kb, u16* __restrict__ Vt) {
  __shared__ u16 As[128 * 64];   // 16 KB
  __shared__ u16 Bs[256 * 64];   // 32 KB
  const int t = threadIdx.x;
  const int w = t >> 6, l = t & 63;
  const int lr = l & 15, lg = l >> 4;
  const int id = blockIdx.x;
  const int r8 = id & 7;
  const int tt = id >> 3;
  const int xt = tt % NXT;
  const int yt = (tt / NXT) * 8 + r8;
  const int m0 = yt * 128, n0 = xt * 256;
  const int wm = (w >> 2) * 64, wn = (w & 3) * 64;

  f32x4 acc[4][4] = {};

  for (int k0 = 0; k0 < 256; k0 += 64) {
    __syncthreads();
#pragma unroll
    for (int j = 0; j < 2; ++j) {
      const int idx = t + j * 512;
      const int row = idx >> 3, c = idx & 7;
      f4 va = *(const f4*)&A[(size_t)(m0 + row) * 256 + k0 + c * 8];
      *(f4*)&As[row * 64 + ((c ^ (row & 7)) * 8)] = va;
    }
#pragma unroll
    for (int j = 0; j < 4; ++j) {
      const int idx = t + j * 512;
      const int row = idx >> 3, c = idx & 7;
      f4 vb = *(const f4*)&Bt[(size_t)(n0 + row) * 256 + k0 + c * 8];
      *(f4*)&Bs[row * 64 + ((c ^ (row & 7)) * 8)] = vb;
    }
    __syncthreads();
#pragma unroll
    for (int kc = 0; kc < 2; ++kc) {
      bf16x8 af[4], bfr[4];
#pragma unroll
      for (int f = 0; f < 4; ++f) {
        int ar = wm + f * 16 + lr;
        af[f] = *(const bf16x8*)&As[ar * 64 + (((kc * 4 + lg) ^ (ar & 7)) * 8)];
        int br = wn + f * 16 + lr;
        bfr[f] = *(const bf16x8*)&Bs[br * 64 + (((kc * 4 + lg) ^ (br & 7)) * 8)];
      }
#pragma unroll
      for (int i = 0; i < 4; ++i)
#pragma unroll
        for (int jn = 0; jn < 4; ++jn)
          acc[i][jn] = __builtin_amdgcn_mfma_f32_16x16x32_bf16(
              af[i], bfr[jn], acc[i][jn], 0, 0, 0);
    }
  }

#pragma unroll
  for (int i = 0; i < 4; ++i) {
    const int mbase = m0 + wm + i * 16 + lg * 4;
#pragma unroll
    for (int jn = 0; jn < 4; ++jn) {
      const int n = n0 + wn + jn * 16 + lr;
      const float bv = bias[n];
      if (EPI == 0) {
#pragma unroll
        for (int r = 0; r < 4; ++r)
          outF[(size_t)(mbase + r) * 256 + n] = acc[i][jn][r] + bv;
      } else {
        if (n < 256) {
#pragma unroll
          for (int r = 0; r < 4; ++r)
            Qb[(size_t)(mbase + r) * 256 + n] = f2b(acc[i][jn][r] + bv);
        } else if (n < 512) {
#pragma unroll
          for (int r = 0; r < 4; ++r)
            Kb[(size_t)(mbase + r) * 256 + (n - 256)] = f2b(acc[i][jn][r] + bv);
        } else {
          const int d = n - 512;
          const int b = mbase >> 10, sl = mbase & 1023;
          bf16x4 pk;
#pragma unroll
          for (int r = 0; r < 4; ++r) pk[r] = f2b(acc[i][jn][r] + bv);
          *(bf16x4*)&Vt[((size_t)b * 256 + d) * 1024 + sl] = pk;
        }
      }
    }
  }
}

// ---------------------------------------------------------------------------
// Fused attention v13: SINGLE-PASS. Block = (b, qt, h) owns 32 q-rows.
// Unnormalized P kept in LDS (bf16, chunk^row XOR swizzle); QK^T computed
// once; PV accumulates unnormalized and is scaled by inv at the end; attn
// written as one coalesced normalized burst from P. 4 waves:
//   QK: wave w -> q-half (w&1), k-half (w>>1);  PV: wave w -> d-slice w*64.
// K: single 16 KB LDS buffer + reg-prefetch (T14); V: reg-prefetched frags.
// LDS = P 64 KB + K 16 KB = 80 KB -> 2 blocks/CU (burst overlaps compute).
// Heavy-first dispatch: zb=id>>6 -> qt=15-(zb>>1), h=1-(zb&1).
// ---------------------------------------------------------------------------
__global__ __launch_bounds__(256) void attn_fused(
    const u16* __restrict__ Qg, const u16* __restrict__ Kg,
    const u16* __restrict__ Vtg, float* __restrict__ attn,
    u16* __restrict__ outa) {
  __shared__ u16 pool[40960];            // 81920 B
  u16* P = pool;                         // [32][1024] bf16, swizzled
  u16* Ks = pool + 32768;                // [32][256] bf16, swizzled
  float* rsF = (float*)(pool + 32768);   // overlays Ks AFTER the main loop

  const int t = threadIdx.x;
  const int w = t >> 6, l = t & 63;
  const int lr = l & 15, lg = l >> 4;
  const int id = blockIdx.x;
  const int b = 8 * (id & 7) + ((id >> 3) & 7);  // batch -> XCD locality
  const int zb = id >> 6;                        // 0..31, heavy tiles first
  const int qt = 15 - (zb >> 1);
  const int h = 1 - (zb & 1);
  const int qrow0 = qt * 64 + h * 32;
  const int last = 2 * qt + h;  // steps = last+1, kcols = (last+1)*32
  const int qh = w & 1, sfh = w >> 1;  // QK work split
  const int d0 = w * 64;               // PV d-slice

  const u16* Kbase = Kg + (size_t)b * SS * DDIM;
  const u16* Vbase = Vtg + (size_t)b * DDIM * SS;

  // Q frags: this wave's 16 q-rows (q-half qh), full D
  bf16x8 qf[8];
  {
    const u16* qp = Qg + ((size_t)(b * SS + qrow0 + qh * 16 + lr)) * DDIM;
#pragma unroll
    for (int kc = 0; kc < 8; ++kc)
      qf[kc] = *(const bf16x8*)&qp[kc * 32 + lg * 8];
  }

  // prologue: K(0) -> regs -> swizzled LDS; V(0) -> frags
  {
    f4 kreg[4];
#pragma unroll
    for (int j = 0; j < 4; ++j) {
      const int cid = t + j * 256;
      const int row = cid >> 5, ch = cid & 31;
      kreg[j] = *(const f4*)&Kbase[(size_t)row * 256 + ch * 8];
#pragma unroll
      for (int jj = 0; jj <= 0; ++jj) {  // keep store adjacent to load
        const int sw = (ch & 24) | ((ch & 7) ^ (row & 7));
        *(f4*)&Ks[row * 256 + sw * 8] = kreg[j];
      }
    }
  }
  __syncthreads();

  bf16x8 vfr[4];
#pragma unroll
  for (int df = 0; df < 4; ++df)
    vfr[df] = *(const bf16x8*)&Vbase[(size_t)(d0 + df * 16 + lr) * SS + lg * 8];

  float ra[4] = {0.f, 0.f, 0.f, 0.f};
  f32x4 oacc[2][4];
#pragma unroll
  for (int qb = 0; qb < 2; ++qb)
#pragma unroll
    for (int df = 0; df < 4; ++df) oacc[qb][df] = (f32x4){0.f, 0.f, 0.f, 0.f};

  for (int kt = 0; kt <= last; ++kt) {
    // prefetch K(kt+1)/V(kt+1) into regs (flight spans the whole step)
    f4 kregN[4];
    bf16x8 vfrN[4];
    if (kt < last) {
#pragma unroll
      for (int j = 0; j < 4; ++j) {
        const int cid = t + j * 256;
        const int row = cid >> 5, ch = cid & 31;
        kregN[j] =
            *(const f4*)&Kbase[(size_t)((kt + 1) * 32 + row) * 256 + ch * 8];
      }
#pragma unroll
      for (int df = 0; df < 4; ++df)
        vfrN[df] = *(const bf16x8*)&Vbase[(size_t)(d0 + df * 16 + lr) * SS +
                                          (kt + 1) * 32 + lg * 8];
    }
    // QK (this wave: 16 q x 16 k) + exp + rowsum + P stash
    {
      const int srow = sfh * 16 + lr;
      f32x4 s = {0.f, 0.f, 0.f, 0.f};
#pragma unroll
      for (int kc = 0; kc < 8; ++kc) {
        const int c = kc * 4 + lg;
        const int ch = (c & 24) | ((c & 7) ^ (srow & 7));
        bf16x8 bfr = *(const bf16x8*)&Ks[srow * 256 + ch * 8];
        s = __builtin_amdgcn_mfma_f32_16x16x32_bf16(qf[kc], bfr, s, 0, 0, 0);
      }
      const int qmin = qrow0 + qh * 16;
      float p[4];
      if (kt * 32 + sfh * 16 + 16 <= qmin) {  // wave-uniform unmasked
#pragma unroll
        for (int r = 0; r < 4; ++r) p[r] = __expf(s[r] * 0.0625f);
      } else {
        const int scol = kt * 32 + sfh * 16 + lr;
#pragma unroll
        for (int r = 0; r < 4; ++r)
          p[r] = (scol <= qmin + lg * 4 + r) ? __expf(s[r] * 0.0625f) : 0.f;
      }
#pragma unroll
      for (int r = 0; r < 4; ++r) {
        ra[r] += p[r];
        const int row = qh * 16 + lg * 4 + r;
        const int col = kt * 32 + sfh * 16 + lr;
        const int c = col >> 3;
        const int sw = (c & ~7) | ((c & 7) ^ (row & 7));
        P[row * 1024 + sw * 8 + (col & 7)] = f2b(p[r]);
      }
    }
    __syncthreads();  // #1: K reads done; P(kt) published
    if (kt < last) {  // K(kt+1) regs -> LDS (WAR-safe after #1)
#pragma unroll
      for (int j = 0; j < 4; ++j) {
        const int cid = t + j * 256;
        const int row = cid >> 5, ch = cid & 31;
        const int sw = (ch & 24) | ((ch & 7) ^ (row & 7));
        *(f4*)&Ks[row * 256 + sw * 8] = kregN[j];
      }
    }
    // PV: wave's 64-d slice for all 32 q-rows (unnormalized P)
#pragma unroll
    for (int qb = 0; qb < 2; ++qb) {
      const int row = qb * 16 + lr;
      const int c = kt * 4 + lg;
      const int sw = (c & ~7) | ((c & 7) ^ (row & 7));
      bf16x8 pa = *(const bf16x8*)&P[row * 1024 + sw * 8];
#pragma unroll
      for (int df = 0; df < 4; ++df)
        oacc[qb][df] = __builtin_amdgcn_mfma_f32_16x16x32_bf16(
            pa, vfr[df], oacc[qb][df], 0, 0, 0);
    }
    if (kt < last) {
#pragma unroll
      for (int df = 0; df < 4; ++df) vfr[df] = vfrN[df];
      __syncthreads();  // #2: Ks(kt+1) published
    }
  }

  // rowsums: butterfly over the 16 lr lanes, then publish partial halves
#pragma unroll
  for (int m = 1; m < 16; m <<= 1)
#pragma unroll
    for (int r = 0; r < 4; ++r) ra[r] += __shfl_xor(ra[r], m, 64);
  if (lr == 0) {
#pragma unroll
    for (int r = 0; r < 4; ++r)
      rsF[sfh * 32 + qh * 16 + lg * 4 + r] = ra[r];  // overlays dead Ks
  }
  __syncthreads();

  // attn burst: normalized full-line writes from P; then zero tail
  {
    float* attnb = attn + ((size_t)(b * SS + qrow0)) * SS;
    const int row = w * 8 + (l >> 3);
    const float invr = 1.0f / (rsF[row] + rsF[32 + row]);
    const int kend = (last + 1) * 32;
    for (int c0 = 0; c0 < kend; c0 += 32) {
      const int col = c0 + (l & 7) * 4;
      const int c = col >> 3;
      const int sw = (c & ~7) | ((c & 7) ^ (row & 7));
      bf16x4 pv = *(const bf16x4*)&P[row * 1024 + sw * 8 + (col & 7)];
      f4 o;
#pragma unroll
      for (int j = 0; j < 4; ++j) o[j] = b2f((u16)pv[j]) * invr;
      *(f4*)&attnb[(size_t)row * SS + col] = o;
    }
    const f4 z = {0.f, 0.f, 0.f, 0.f};
    for (int c0 = kend; c0 < SS; c0 += 32)
      *(f4*)&attnb[(size_t)row * SS + c0 + (l & 7) * 4] = z;
  }
  __syncthreads();  // P reads done before restage overwrite

  // O: scale by inv, restage through P region, full-line bf16 stores
#pragma unroll
  for (int qb = 0; qb < 2; ++qb) {
#pragma unroll
    for (int r = 0; r < 4; ++r) {
      const int row = qb * 16 + lg * 4 + r;
      const float invv = 1.0f / (rsF[row] + rsF[32 + row]);
#pragma unroll
      for (int df = 0; df < 4; ++df)
        pool[row * 264 + d0 + df * 16 + lr] = f2b(oacc[qb][df][r] * invv);
    }
  }
  __syncthreads();
  {
    const int row = t >> 3;
    const int cb = (t & 7) * 32;
    u16* og = outa + ((size_t)(b * SS + qrow0 + row)) * DDIM + cb;
#pragma unroll
    for (int k = 0; k < 4; ++k) {
      bf16x8 v = *(const bf16x8*)&pool[row * 264 + cb + k * 8];
      *(bf16x8*)&og[k * 8] = v;
    }
  }
}

// ---------------------------------------------------------------------------
extern "C" void kernel_launch(void* const* d_in, const int* in_sizes, int n_in,
                              void* d_out, int out_size, void* d_ws,
                              size_t ws_size, hipStream_t stream) {
  const float* x    = (const float*)d_in[0];
  const float* Wqkv = (const float*)d_in[1];
  const float* bqkv = (const float*)d_in[2];
  const float* Wout = (const float*)d_in[3];
  const float* bout = (const float*)d_in[4];

  float* out  = (float*)d_out;                 // [B,S,D] f32
  float* attn = out + (size_t)BB * SS * DDIM;  // [B,1,S,S] f32

  const size_t NTOK = (size_t)BB * SS;  // 65536
  u16* ws = (u16*)d_ws;
  u16* xb    = ws;
  u16* Qb    = xb + NTOK * DDIM;
  u16* Kb    = Qb + NTOK * DDIM;
  u16* Vt    = Kb + NTOK * DDIM;  // [B][256][1024]
  u16* outa  = Vt + NTOK * DDIM;
  u16* Wqkvt = outa + NTOK * DDIM;
  u16* Woutt = Wqkvt + 768 * 256;

  cast_x<<<2048, 256, 0, stream>>>(x, xb, (int)(NTOK * DDIM / 8));
  cast_w<<<768, 256, 0, stream>>>(Wqkv, Wout, Wqkvt, Woutt);

  gemm_mfma<1, 3><<<1536, 512, 0, stream>>>(xb, Wqkvt, bqkv, nullptr, Qb, Kb,
                                            Vt);
  attn_fused<<<2048, 256, 0, stream>>>(Qb, Kb, Vt, attn, outa);
  gemm_mfma<0, 1><<<512, 512, 0, stream>>>(outa, Woutt, bout, out, nullptr,
                                           nullptr, nullptr);
}

// Round 19
// 246.593 us; speedup vs baseline: 1.0139x; 1.0139x over previous
//
#include <hip/hip_runtime.h>
#include <hip/hip_bf16.h>

#define BB 64
#define SS 1024
#define DDIM 256

typedef unsigned short u16;
typedef unsigned int u32;
typedef __attribute__((ext_vector_type(4))) float f4;
typedef __attribute__((ext_vector_type(8))) short bf16x8;
typedef __attribute__((ext_vector_type(4))) short bf16x4;
typedef __attribute__((ext_vector_type(4))) float f32x4;

__device__ inline u16 f2b(float f) {
  unsigned int u = __float_as_uint(f);
  unsigned int r = (u + 0x7fffu + ((u >> 16) & 1u)) >> 16;
  return (u16)r;
}
__device__ inline float b2f(u16 v) {
  return __uint_as_float(((u32)v) << 16);
}

// ---------------------------------------------------------------------------
// One launch: cast x (grid-stride) + cast/transpose both weight matrices.
__global__ __launch_bounds__(256) void cast_all(
    const float* __restrict__ x, const float* __restrict__ Wqkv,
    const float* __restrict__ Wout, u16* __restrict__ xb,
    u16* __restrict__ Wqkvt, u16* __restrict__ Woutt, int n8) {
  const int gid = blockIdx.x * 256 + threadIdx.x;
  if (gid < 256 * 768) {
    int k = gid / 768, n = gid % 768;
    Wqkvt[n * 256 + k] = f2b(Wqkv[gid]);
  }
  if (gid < 256 * 256) {
    int k = gid / 256, n = gid % 256;
    Woutt[n * 256 + k] = f2b(Wout[gid]);
  }
  const int stride = gridDim.x * 256;
  for (int i = gid; i < n8; i += stride) {
    f4 a = ((const f4*)x)[2 * i];
    f4 b = ((const f4*)x)[2 * i + 1];
    bf16x8 o;
    o[0] = f2b(a[0]); o[1] = f2b(a[1]); o[2] = f2b(a[2]); o[3] = f2b(a[3]);
    o[4] = f2b(b[0]); o[5] = f2b(b[1]); o[6] = f2b(b[2]); o[7] = f2b(b[3]);
    ((bf16x8*)xb)[i] = o;
  }
}

// ---------------------------------------------------------------------------
// MFMA GEMM (round-15, kept for QKV only): 128x256 tile, 8 waves, BK=64.
// ---------------------------------------------------------------------------
template <int NXT>
__global__ __launch_bounds__(512) void gemm_qkv(
    const u16* __restrict__ A, const u16* __restrict__ Bt,
    const float* __restrict__ bias, u16* __restrict__ Qb,
    u16* __restrict__ Kb, u16* __restrict__ Vt) {
  __shared__ u16 As[128 * 64];   // 16 KB
  __shared__ u16 Bs[256 * 64];   // 32 KB
  const int t = threadIdx.x;
  const int w = t >> 6, l = t & 63;
  const int lr = l & 15, lg = l >> 4;
  const int id = blockIdx.x;
  const int r8 = id & 7;
  const int tt = id >> 3;
  const int xt = tt % NXT;
  const int yt = (tt / NXT) * 8 + r8;
  const int m0 = yt * 128, n0 = xt * 256;
  const int wm = (w >> 2) * 64, wn = (w & 3) * 64;

  f32x4 acc[4][4] = {};

  for (int k0 = 0; k0 < 256; k0 += 64) {
    __syncthreads();
#pragma unroll
    for (int j = 0; j < 2; ++j) {
      const int idx = t + j * 512;
      const int row = idx >> 3, c = idx & 7;
      f4 va = *(const f4*)&A[(size_t)(m0 + row) * 256 + k0 + c * 8];
      *(f4*)&As[row * 64 + ((c ^ (row & 7)) * 8)] = va;
    }
#pragma unroll
    for (int j = 0; j < 4; ++j) {
      const int idx = t + j * 512;
      const int row = idx >> 3, c = idx & 7;
      f4 vb = *(const f4*)&Bt[(size_t)(n0 + row) * 256 + k0 + c * 8];
      *(f4*)&Bs[row * 64 + ((c ^ (row & 7)) * 8)] = vb;
    }
    __syncthreads();
#pragma unroll
    for (int kc = 0; kc < 2; ++kc) {
      bf16x8 af[4], bfr[4];
#pragma unroll
      for (int f = 0; f < 4; ++f) {
        int ar = wm + f * 16 + lr;
        af[f] = *(const bf16x8*)&As[ar * 64 + (((kc * 4 + lg) ^ (ar & 7)) * 8)];
        int br = wn + f * 16 + lr;
        bfr[f] = *(const bf16x8*)&Bs[br * 64 + (((kc * 4 + lg) ^ (br & 7)) * 8)];
      }
#pragma unroll
      for (int i = 0; i < 4; ++i)
#pragma unroll
        for (int jn = 0; jn < 4; ++jn)
          acc[i][jn] = __builtin_amdgcn_mfma_f32_16x16x32_bf16(
              af[i], bfr[jn], acc[i][jn], 0, 0, 0);
    }
  }

#pragma unroll
  for (int i = 0; i < 4; ++i) {
    const int mbase = m0 + wm + i * 16 + lg * 4;
#pragma unroll
    for (int jn = 0; jn < 4; ++jn) {
      const int n = n0 + wn + jn * 16 + lr;
      const float bv = bias[n];
      if (n < 256) {
#pragma unroll
        for (int r = 0; r < 4; ++r)
          Qb[(size_t)(mbase + r) * 256 + n] = f2b(acc[i][jn][r] + bv);
      } else if (n < 512) {
#pragma unroll
        for (int r = 0; r < 4; ++r)
          Kb[(size_t)(mbase + r) * 256 + (n - 256)] = f2b(acc[i][jn][r] + bv);
      } else {
        const int d = n - 512;
        const int b = mbase >> 10, sl = mbase & 1023;
        bf16x4 pk;
#pragma unroll
        for (int r = 0; r < 4; ++r) pk[r] = f2b(acc[i][jn][r] + bv);
        *(bf16x4*)&Vt[((size_t)b * 256 + d) * 1024 + sl] = pk;
      }
    }
  }
}

// ---------------------------------------------------------------------------
// Fused attention v14 = v13 single-pass + FUSED OUTPUT PROJECTION.
// Block = (b, qt, h) owns 32 q-rows. Unnormalized P in LDS (swizzled);
// QK^T once; PV unnormalized, scaled at end. Epilogue: O_n bf16 -> Ks region
// (swizzled), mini-GEMM vs Woutt (B-frags global, L2-hot), bias, f32 stage
// in P region (pitch 260), coalesced burst to out. No outa, no out-GEMM.
// ---------------------------------------------------------------------------
__global__ __launch_bounds__(256) void attn_fused(
    const u16* __restrict__ Qg, const u16* __restrict__ Kg,
    const u16* __restrict__ Vtg, const u16* __restrict__ Woutt,
    const float* __restrict__ bout, float* __restrict__ attn,
    float* __restrict__ out) {
  __shared__ u16 pool[40960];            // 81920 B
  u16* P = pool;                         // [32][1024] bf16, swizzled
  u16* Ks = pool + 32768;                // [32][256] bf16, swizzled
  float* rsF = (float*)(pool + 32768);   // overlays Ks after main loop
  float* fout = (float*)pool;            // [32][260] f32, overlays P at end

  const int t = threadIdx.x;
  const int w = t >> 6, l = t & 63;
  const int lr = l & 15, lg = l >> 4;
  const int id = blockIdx.x;
  const int b = 8 * (id & 7) + ((id >> 3) & 7);  // batch -> XCD locality
  const int zb = id >> 6;                        // 0..31, heavy tiles first
  const int qt = 15 - (zb >> 1);
  const int h = 1 - (zb & 1);
  const int qrow0 = qt * 64 + h * 32;
  const int last = 2 * qt + h;
  const int qh = w & 1, sfh = w >> 1;  // QK work split
  const int d0 = w * 64;               // PV d-slice / out n-slice

  const u16* Kbase = Kg + (size_t)b * SS * DDIM;
  const u16* Vbase = Vtg + (size_t)b * DDIM * SS;

  // Q frags
  bf16x8 qf[8];
  {
    const u16* qp = Qg + ((size_t)(b * SS + qrow0 + qh * 16 + lr)) * DDIM;
#pragma unroll
    for (int kc = 0; kc < 8; ++kc)
      qf[kc] = *(const bf16x8*)&qp[kc * 32 + lg * 8];
  }

  // prologue: K(0) -> regs -> swizzled LDS
  {
#pragma unroll
    for (int j = 0; j < 4; ++j) {
      const int cid = t + j * 256;
      const int row = cid >> 5, ch = cid & 31;
      f4 kv = *(const f4*)&Kbase[(size_t)row * 256 + ch * 8];
      const int sw = (ch & 24) | ((ch & 7) ^ (row & 7));
      *(f4*)&Ks[row * 256 + sw * 8] = kv;
    }
  }
  __syncthreads();

  bf16x8 vfr[4];
#pragma unroll
  for (int df = 0; df < 4; ++df)
    vfr[df] = *(const bf16x8*)&Vbase[(size_t)(d0 + df * 16 + lr) * SS + lg * 8];

  float ra[4] = {0.f, 0.f, 0.f, 0.f};
  f32x4 oacc[2][4];
#pragma unroll
  for (int qb = 0; qb < 2; ++qb)
#pragma unroll
    for (int df = 0; df < 4; ++df) oacc[qb][df] = (f32x4){0.f, 0.f, 0.f, 0.f};

  for (int kt = 0; kt <= last; ++kt) {
    // prefetch K(kt+1)/V(kt+1) into regs
    f4 kregN[4];
    bf16x8 vfrN[4];
    if (kt < last) {
#pragma unroll
      for (int j = 0; j < 4; ++j) {
        const int cid = t + j * 256;
        const int row = cid >> 5, ch = cid & 31;
        kregN[j] =
            *(const f4*)&Kbase[(size_t)((kt + 1) * 32 + row) * 256 + ch * 8];
      }
#pragma unroll
      for (int df = 0; df < 4; ++df)
        vfrN[df] = *(const bf16x8*)&Vbase[(size_t)(d0 + df * 16 + lr) * SS +
                                          (kt + 1) * 32 + lg * 8];
    }
    // QK + exp + rowsum + P stash
    {
      const int srow = sfh * 16 + lr;
      f32x4 s = {0.f, 0.f, 0.f, 0.f};
#pragma unroll
      for (int kc = 0; kc < 8; ++kc) {
        const int c = kc * 4 + lg;
        const int ch = (c & 24) | ((c & 7) ^ (srow & 7));
        bf16x8 bfr = *(const bf16x8*)&Ks[srow * 256 + ch * 8];
        s = __builtin_amdgcn_mfma_f32_16x16x32_bf16(qf[kc], bfr, s, 0, 0, 0);
      }
      const int qmin = qrow0 + qh * 16;
      float p[4];
      if (kt * 32 + sfh * 16 + 16 <= qmin) {
#pragma unroll
        for (int r = 0; r < 4; ++r) p[r] = __expf(s[r] * 0.0625f);
      } else {
        const int scol = kt * 32 + sfh * 16 + lr;
#pragma unroll
        for (int r = 0; r < 4; ++r)
          p[r] = (scol <= qmin + lg * 4 + r) ? __expf(s[r] * 0.0625f) : 0.f;
      }
#pragma unroll
      for (int r = 0; r < 4; ++r) {
        ra[r] += p[r];
        const int row = qh * 16 + lg * 4 + r;
        const int col = kt * 32 + sfh * 16 + lr;
        const int c = col >> 3;
        const int sw = (c & ~7) | ((c & 7) ^ (row & 7));
        P[row * 1024 + sw * 8 + (col & 7)] = f2b(p[r]);
      }
    }
    __syncthreads();  // #1: K reads done; P(kt) published
    if (kt < last) {
#pragma unroll
      for (int j = 0; j < 4; ++j) {
        const int cid = t + j * 256;
        const int row = cid >> 5, ch = cid & 31;
        const int sw = (ch & 24) | ((ch & 7) ^ (row & 7));
        *(f4*)&Ks[row * 256 + sw * 8] = kregN[j];
      }
    }
    // PV (unnormalized P)
#pragma unroll
    for (int qb = 0; qb < 2; ++qb) {
      const int row = qb * 16 + lr;
      const int c = kt * 4 + lg;
      const int sw = (c & ~7) | ((c & 7) ^ (row & 7));
      bf16x8 pa = *(const bf16x8*)&P[row * 1024 + sw * 8];
#pragma unroll
      for (int df = 0; df < 4; ++df)
        oacc[qb][df] = __builtin_amdgcn_mfma_f32_16x16x32_bf16(
            pa, vfr[df], oacc[qb][df], 0, 0, 0);
    }
    if (kt < last) {
#pragma unroll
      for (int df = 0; df < 4; ++df) vfr[df] = vfrN[df];
      __syncthreads();  // #2: Ks(kt+1) published
    }
  }

  // rowsums: butterfly, publish to rsF (overlays dead Ks)
#pragma unroll
  for (int m = 1; m < 16; m <<= 1)
#pragma unroll
    for (int r = 0; r < 4; ++r) ra[r] += __shfl_xor(ra[r], m, 64);
  if (lr == 0) {
#pragma unroll
    for (int r = 0; r < 4; ++r)
      rsF[sfh * 32 + qh * 16 + lg * 4 + r] = ra[r];
  }
  __syncthreads();

  // read inv for my oacc rows into regs (rsF dies when Ks is re-used)
  float invq[2][4];
#pragma unroll
  for (int qb = 0; qb < 2; ++qb)
#pragma unroll
    for (int r = 0; r < 4; ++r) {
      const int row = qb * 16 + lg * 4 + r;
      invq[qb][r] = 1.0f / (rsF[row] + rsF[32 + row]);
    }

  // attn burst: normalized full-line writes from P; then zero tail
  {
    float* attnb = attn + ((size_t)(b * SS + qrow0)) * SS;
    const int row = w * 8 + (l >> 3);
    const float invr = 1.0f / (rsF[row] + rsF[32 + row]);
    const int kend = (last + 1) * 32;
    for (int c0 = 0; c0 < kend; c0 += 32) {
      const int col = c0 + (l & 7) * 4;
      const int c = col >> 3;
      const int sw = (c & ~7) | ((c & 7) ^ (row & 7));
      bf16x4 pv = *(const bf16x4*)&P[row * 1024 + sw * 8 + (col & 7)];
      f4 o;
#pragma unroll
      for (int j = 0; j < 4; ++j) o[j] = b2f((u16)pv[j]) * invr;
      *(f4*)&attnb[(size_t)row * SS + col] = o;
    }
    const f4 z = {0.f, 0.f, 0.f, 0.f};
    for (int c0 = kend; c0 < SS; c0 += 32)
      *(f4*)&attnb[(size_t)row * SS + c0 + (l & 7) * 4] = z;
  }
  __syncthreads();  // P/rsF reads done; Ks and P regions free

  // O_n (bf16) -> Ks region, chunk^row swizzle (A operand for out-proj)
#pragma unroll
  for (int qb = 0; qb < 2; ++qb)
#pragma unroll
    for (int df = 0; df < 4; ++df)
#pragma unroll
      for (int r = 0; r < 4; ++r) {
        const int row = qb * 16 + lg * 4 + r;
        const int col = d0 + df * 16 + lr;
        const int c = col >> 3;
        const int sw = (c & ~7) | ((c & 7) ^ (row & 7));
        Ks[row * 256 + sw * 8 + (col & 7)] = f2b(oacc[qb][df][r] * invq[qb][r]);
      }
  __syncthreads();

  // mini out-proj: wave w -> n-slice d0; A from Ks, B from global Woutt.
  f32x4 wacc[2][4];
#pragma unroll
  for (int qb = 0; qb < 2; ++qb)
#pragma unroll
    for (int df = 0; df < 4; ++df) wacc[qb][df] = (f32x4){0.f, 0.f, 0.f, 0.f};
#pragma unroll
  for (int kc = 0; kc < 8; ++kc) {
    bf16x8 af[2], bfr[4];
#pragma unroll
    for (int qb = 0; qb < 2; ++qb) {
      const int row = qb * 16 + lr;
      const int c = kc * 4 + lg;
      const int sw = (c & ~7) | ((c & 7) ^ (row & 7));
      af[qb] = *(const bf16x8*)&Ks[row * 256 + sw * 8];
    }
#pragma unroll
    for (int df = 0; df < 4; ++df)
      bfr[df] = *(const bf16x8*)&Woutt[(size_t)(d0 + df * 16 + lr) * 256 +
                                       kc * 32 + lg * 8];
#pragma unroll
    for (int qb = 0; qb < 2; ++qb)
#pragma unroll
      for (int df = 0; df < 4; ++df)
        wacc[qb][df] = __builtin_amdgcn_mfma_f32_16x16x32_bf16(
            af[qb], bfr[df], wacc[qb][df], 0, 0, 0);
  }
  // + bias, stage f32 in fout (P region free), pitch 260
#pragma unroll
  for (int df = 0; df < 4; ++df) {
    const int n = d0 + df * 16 + lr;
    const float bv = bout[n];
#pragma unroll
    for (int qb = 0; qb < 2; ++qb)
#pragma unroll
      for (int r = 0; r < 4; ++r)
        fout[(qb * 16 + lg * 4 + r) * 260 + n] = wacc[qb][df][r] + bv;
  }
  __syncthreads();

  // coalesced out burst: 8 threads/row, 128 B each
  {
    const int row = t >> 3;
    const int cb = (t & 7) * 32;
    float* og = out + ((size_t)(b * SS + qrow0 + row)) * DDIM + cb;
#pragma unroll
    for (int k = 0; k < 8; ++k) {
      f4 v = *(const f4*)&fout[row * 260 + cb + k * 4];
      *(f4*)&og[k * 4] = v;
    }
  }
}

// ---------------------------------------------------------------------------
extern "C" void kernel_launch(void* const* d_in, const int* in_sizes, int n_in,
                              void* d_out, int out_size, void* d_ws,
                              size_t ws_size, hipStream_t stream) {
  const float* x    = (const float*)d_in[0];
  const float* Wqkv = (const float*)d_in[1];
  const float* bqkv = (const float*)d_in[2];
  const float* Wout = (const float*)d_in[3];
  const float* bout = (const float*)d_in[4];

  float* out  = (float*)d_out;                 // [B,S,D] f32
  float* attn = out + (size_t)BB * SS * DDIM;  // [B,1,S,S] f32

  const size_t NTOK = (size_t)BB * SS;  // 65536
  u16* ws = (u16*)d_ws;
  u16* xb    = ws;
  u16* Qb    = xb + NTOK * DDIM;
  u16* Kb    = Qb + NTOK * DDIM;
  u16* Vt    = Kb + NTOK * DDIM;  // [B][256][1024]
  u16* Wqkvt = Vt + NTOK * DDIM;
  u16* Woutt = Wqkvt + 768 * 256;

  cast_all<<<2048, 256, 0, stream>>>(x, Wqkv, Wout, xb, Wqkvt, Woutt,
                                     (int)(NTOK * DDIM / 8));
  gemm_qkv<3><<<1536, 512, 0, stream>>>(xb, Wqkvt, bqkv, Qb, Kb, Vt);
  attn_fused<<<2048, 256, 0, stream>>>(Qb, Kb, Vt, Woutt, bout, attn, out);
}